// Round 1
// baseline (118.654 us; speedup 1.0000x reference)
//
#include <hip/hip_runtime.h>

// EMD / min-cost-assignment over 6 points, D=64, B=32768.
// cost(perm) = T - 2 * sum_n p_n . t_perm(n)  with T = sum|p|^2 + sum|t|^2
// min over 720 perms == T - 2 * max-assignment(dot matrix), solved by
// Held-Karp DP over 2^6 subsets, fully unrolled (static register indexing).

#define BLOCK 256

__device__ __forceinline__ float dot4(float4 a, float4 b) {
    return a.x * b.x + a.y * b.y + a.z * b.z + a.w * b.w;
}

// compile-time popcount for 6-bit subsets (folds after full unroll)
#define PC6(S) (((S)&1) + (((S)>>1)&1) + (((S)>>2)&1) + (((S)>>3)&1) + (((S)>>4)&1) + (((S)>>5)&1))

__global__ __launch_bounds__(BLOCK, 2)
void emd_kernel(const float* __restrict__ preds,
                const float* __restrict__ targets,
                float* __restrict__ out, int B) {
    const int t    = blockIdx.x * BLOCK + threadIdx.x;
    const int b    = t >> 2;      // batch
    const int h    = t & 3;       // 4-lane split of the D=64 dims
    const int lane = threadIdx.x & 63;

    float best = 0.0f;
    if (b < B) {
        // lane h owns float4 slots {h, h+4, h+8, h+12} of each 16-float4 row,
        // i.e. the h-th 16B of every 64B chunk -> each 4-lane group reads a
        // contiguous 64B line per load instruction.
        const float* P = preds   + (size_t)b * 384 + h * 4;
        const float* T = targets + (size_t)b * 384 + h * 4;

        float d[6][6];
#pragma unroll
        for (int n = 0; n < 6; ++n)
#pragma unroll
            for (int m = 0; m < 6; ++m) d[n][m] = 0.0f;
        float tn = 0.0f;  // partial sum of |p|^2 + |t|^2 over this lane's dims

#pragma unroll
        for (int c = 0; c < 4; ++c) {      // 64B chunk index within each row
            float4 pv[6], tv[6];
#pragma unroll
            for (int n = 0; n < 6; ++n)
                pv[n] = *(const float4*)(P + n * 64 + c * 16);
#pragma unroll
            for (int m = 0; m < 6; ++m)
                tv[m] = *(const float4*)(T + m * 64 + c * 16);
#pragma unroll
            for (int n = 0; n < 6; ++n) {
                tn += dot4(pv[n], pv[n]) + dot4(tv[n], tv[n]);
#pragma unroll
                for (int m = 0; m < 6; ++m)
                    d[n][m] += dot4(pv[n], tv[m]);
            }
        }

        // combine the 4 per-lane partials (lanes differ only in low 2 bits)
#pragma unroll
        for (int o = 1; o <= 2; o <<= 1) {
#pragma unroll
            for (int n = 0; n < 6; ++n)
#pragma unroll
                for (int m = 0; m < 6; ++m)
                    d[n][m] += __shfl_xor(d[n][m], o);
            tn += __shfl_xor(tn, o);
        }

        // Held-Karp: g[S] = max assignment of preds 0..|S|-1 to target set S.
        // Fully unrolled: every index is compile-time constant -> registers.
        float g[64];
        g[0] = 0.0f;
#pragma unroll
        for (int S = 1; S < 64; ++S) {
            float bst = -3.4e38f;
#pragma unroll
            for (int m = 0; m < 6; ++m) {
                if (S & (1 << m)) {
                    float cand = g[S ^ (1 << m)] + d[PC6(S) - 1][m];
                    bst = fmaxf(bst, cand);
                }
            }
            g[S] = bst;
        }
        best = tn - 2.0f * g[63];   // min over all 720 permutations
    }

    // block reduction: only one lane per 4-group contributes
    float v = (h == 0) ? best : 0.0f;
#pragma unroll
    for (int o = 4; o < 64; o <<= 1) v += __shfl_xor(v, o);

    __shared__ float wsum[BLOCK / 64];
    const int wid = threadIdx.x >> 6;
    if (lane == 0) wsum[wid] = v;
    __syncthreads();
    if (threadIdx.x == 0) {
        float s = 0.0f;
#pragma unroll
        for (int i = 0; i < BLOCK / 64; ++i) s += wsum[i];
        atomicAdd(out, s);
    }
}

extern "C" void kernel_launch(void* const* d_in, const int* in_sizes, int n_in,
                              void* d_out, int out_size, void* d_ws, size_t ws_size,
                              hipStream_t stream) {
    const float* preds   = (const float*)d_in[0];
    const float* targets = (const float*)d_in[1];
    float* out = (float*)d_out;
    const int B = in_sizes[0] / 384;   // 6 * 64 floats per batch

    hipMemsetAsync(out, 0, sizeof(float), stream);

    const int total = B * 4;           // 4 lanes per batch
    const int grid  = (total + BLOCK - 1) / BLOCK;
    emd_kernel<<<grid, BLOCK, 0, stream>>>(preds, targets, out, B);
}

// Round 2
// 116.339 us; speedup vs baseline: 1.0199x; 1.0199x over previous
//
#include <hip/hip_runtime.h>

// EMD / min-cost-assignment over 6 points, D=64, B=32768.
// cost(perm) = T - 2 * sum_n p_n . t_perm(n)  with T = sum|p|^2 + sum|t|^2
// min over 720 perms == T - 2 * max-assignment(dot matrix), solved by
// Held-Karp DP over 2^6 subsets, fully unrolled (static register indexing).
//
// R2: 8 lanes per batch (was 4) -> 4096 waves = 4 waves/SIMD resident
// (launch_bounds(256,4), VGPR<=128), 128B-contiguous per-group loads.

#define BLOCK 256

__device__ __forceinline__ float dot4(float4 a, float4 b) {
    return a.x * b.x + a.y * b.y + a.z * b.z + a.w * b.w;
}

// compile-time popcount for 6-bit subsets (folds after full unroll)
#define PC6(S) (((S)&1) + (((S)>>1)&1) + (((S)>>2)&1) + (((S)>>3)&1) + (((S)>>4)&1) + (((S)>>5)&1))

__global__ __launch_bounds__(BLOCK, 4)
void emd_kernel(const float* __restrict__ preds,
                const float* __restrict__ targets,
                float* __restrict__ out) {
    const int t    = blockIdx.x * BLOCK + threadIdx.x;
    const int b    = t >> 3;      // batch (grid is exact: B*8 threads)
    const int h    = t & 7;       // 8-lane split of the D=64 dims
    const int lane = threadIdx.x & 63;

    // lane h owns float4 slots {h, h+8} of each 16-float4 row: the h-th 16B
    // of each 128B half -> every load instr covers 128B contiguous per group.
    const float* P = preds   + (size_t)b * 384 + h * 4;
    const float* T = targets + (size_t)b * 384 + h * 4;

    float d[6][6];
#pragma unroll
    for (int n = 0; n < 6; ++n)
#pragma unroll
        for (int m = 0; m < 6; ++m) d[n][m] = 0.0f;
    float tn = 0.0f;  // partial |p|^2 + |t|^2 over this lane's dims

#pragma unroll
    for (int c = 0; c < 2; ++c) {      // 128B half of each 256B row
        float4 pv[6], tv[6];
#pragma unroll
        for (int n = 0; n < 6; ++n)
            pv[n] = *(const float4*)(P + n * 64 + c * 32);
#pragma unroll
        for (int m = 0; m < 6; ++m)
            tv[m] = *(const float4*)(T + m * 64 + c * 32);
#pragma unroll
        for (int n = 0; n < 6; ++n) {
            tn += dot4(pv[n], pv[n]) + dot4(tv[n], tv[n]);
#pragma unroll
            for (int m = 0; m < 6; ++m)
                d[n][m] += dot4(pv[n], tv[m]);
        }
    }

    // combine the 8 per-lane partials (lanes differ only in low 3 bits)
#pragma unroll
    for (int o = 1; o <= 4; o <<= 1) {
#pragma unroll
        for (int n = 0; n < 6; ++n)
#pragma unroll
            for (int m = 0; m < 6; ++m)
                d[n][m] += __shfl_xor(d[n][m], o);
        tn += __shfl_xor(tn, o);
    }

    // Held-Karp: g[S] = max assignment of preds 0..|S|-1 to target set S.
    // Fully unrolled: every index is compile-time constant -> registers.
    float g[64];
    g[0] = 0.0f;
#pragma unroll
    for (int S = 1; S < 64; ++S) {
        float bst = -3.4e38f;
#pragma unroll
        for (int m = 0; m < 6; ++m) {
            if (S & (1 << m)) {
                float cand = g[S ^ (1 << m)] + d[PC6(S) - 1][m];
                bst = fmaxf(bst, cand);
            }
        }
        g[S] = bst;
    }
    const float best = tn - 2.0f * g[63];   // min over all 720 permutations

    // block reduction: one lane per 8-group contributes
    float v = (h == 0) ? best : 0.0f;
#pragma unroll
    for (int o = 8; o < 64; o <<= 1) v += __shfl_xor(v, o);

    __shared__ float wsum[BLOCK / 64];
    const int wid = threadIdx.x >> 6;
    if (lane == 0) wsum[wid] = v;
    __syncthreads();
    if (threadIdx.x == 0) {
        float s = 0.0f;
#pragma unroll
        for (int i = 0; i < BLOCK / 64; ++i) s += wsum[i];
        atomicAdd(out, s);
    }
}

extern "C" void kernel_launch(void* const* d_in, const int* in_sizes, int n_in,
                              void* d_out, int out_size, void* d_ws, size_t ws_size,
                              hipStream_t stream) {
    const float* preds   = (const float*)d_in[0];
    const float* targets = (const float*)d_in[1];
    float* out = (float*)d_out;
    const int B = in_sizes[0] / 384;   // 6 * 64 floats per batch

    hipMemsetAsync(out, 0, sizeof(float), stream);

    const int total = B * 8;           // 8 lanes per batch
    const int grid  = (total + BLOCK - 1) / BLOCK;
    emd_kernel<<<grid, BLOCK, 0, stream>>>(preds, targets, out);
}

// Round 5
// 115.410 us; speedup vs baseline: 1.0281x; 1.0080x over previous
//
#include <hip/hip_runtime.h>

// EMD / min-cost-assignment over 6 points, D=64, B=32768.
// cost(perm) = T - 2 * sum_n p_n . t_perm(n)  with T = sum|p|^2 + sum|t|^2
// min over 720 perms == T - 2 * max-assignment(dot matrix), solved by
// Held-Karp DP over 2^6 subsets, fully unrolled (static register indexing).
//
// R3 (2nd resubmit; rounds 3/4 hit infra failures, never measured): drop the
// 1024-way single-address atomicAdd epilogue (cross-XCD same-line atomics
// serialize); stage-1 writes per-block partials to d_ws, stage-2 (1 block)
// reduces them into out[0]. Loads/DP unchanged from R2.

#define BLOCK 256

__device__ __forceinline__ float dot4(float4 a, float4 b) {
    return a.x * b.x + a.y * b.y + a.z * b.z + a.w * b.w;
}

// compile-time popcount for 6-bit subsets (folds after full unroll)
#define PC6(S) (((S)&1) + (((S)>>1)&1) + (((S)>>2)&1) + (((S)>>3)&1) + (((S)>>4)&1) + (((S)>>5)&1))

__global__ __launch_bounds__(BLOCK, 4)
void emd_kernel(const float* __restrict__ preds,
                const float* __restrict__ targets,
                float* __restrict__ partials) {
    const int t    = blockIdx.x * BLOCK + threadIdx.x;
    const int b    = t >> 3;      // batch (grid is exact: B*8 threads)
    const int h    = t & 7;       // 8-lane split of the D=64 dims
    const int lane = threadIdx.x & 63;

    // lane h owns float4 slots {h, h+8} of each 16-float4 row: the h-th 16B
    // of each 128B half -> every load instr covers 128B contiguous per group.
    const float* P = preds   + (size_t)b * 384 + h * 4;
    const float* T = targets + (size_t)b * 384 + h * 4;

    float d[6][6];
#pragma unroll
    for (int n = 0; n < 6; ++n)
#pragma unroll
        for (int m = 0; m < 6; ++m) d[n][m] = 0.0f;
    float tn = 0.0f;  // partial |p|^2 + |t|^2 over this lane's dims

#pragma unroll
    for (int c = 0; c < 2; ++c) {      // 128B half of each 256B row
        float4 pv[6], tv[6];
#pragma unroll
        for (int n = 0; n < 6; ++n)
            pv[n] = *(const float4*)(P + n * 64 + c * 32);
#pragma unroll
        for (int m = 0; m < 6; ++m)
            tv[m] = *(const float4*)(T + m * 64 + c * 32);
#pragma unroll
        for (int n = 0; n < 6; ++n) {
            tn += dot4(pv[n], pv[n]) + dot4(tv[n], tv[n]);
#pragma unroll
            for (int m = 0; m < 6; ++m)
                d[n][m] += dot4(pv[n], tv[m]);
        }
    }

    // combine the 8 per-lane partials (lanes differ only in low 3 bits)
#pragma unroll
    for (int o = 1; o <= 4; o <<= 1) {
#pragma unroll
        for (int n = 0; n < 6; ++n)
#pragma unroll
            for (int m = 0; m < 6; ++m)
                d[n][m] += __shfl_xor(d[n][m], o);
        tn += __shfl_xor(tn, o);
    }

    // Held-Karp: g[S] = max assignment of preds 0..|S|-1 to target set S.
    // Fully unrolled: every index is compile-time constant -> registers.
    float g[64];
    g[0] = 0.0f;
#pragma unroll
    for (int S = 1; S < 64; ++S) {
        float bst = -3.4e38f;
#pragma unroll
        for (int m = 0; m < 6; ++m) {
            if (S & (1 << m)) {
                float cand = g[S ^ (1 << m)] + d[PC6(S) - 1][m];
                bst = fmaxf(bst, cand);
            }
        }
        g[S] = bst;
    }
    const float best = tn - 2.0f * g[63];   // min over all 720 permutations

    // block reduction: one lane per 8-group contributes
    float v = (h == 0) ? best : 0.0f;
#pragma unroll
    for (int o = 8; o < 64; o <<= 1) v += __shfl_xor(v, o);

    __shared__ float wsum[BLOCK / 64];
    const int wid = threadIdx.x >> 6;
    if (lane == 0) wsum[wid] = v;
    __syncthreads();
    if (threadIdx.x == 0) {
        float s = 0.0f;
#pragma unroll
        for (int i = 0; i < BLOCK / 64; ++i) s += wsum[i];
        partials[blockIdx.x] = s;   // plain store, no atomic
    }
}

__global__ __launch_bounds__(256)
void reduce_kernel(const float* __restrict__ partials,
                   float* __restrict__ out, int n) {
    float v = 0.0f;
    for (int i = threadIdx.x; i < n; i += 256) v += partials[i];
#pragma unroll
    for (int o = 1; o < 64; o <<= 1) v += __shfl_xor(v, o);
    __shared__ float s[4];
    if ((threadIdx.x & 63) == 0) s[threadIdx.x >> 6] = v;
    __syncthreads();
    if (threadIdx.x == 0) out[0] = s[0] + s[1] + s[2] + s[3];
}

extern "C" void kernel_launch(void* const* d_in, const int* in_sizes, int n_in,
                              void* d_out, int out_size, void* d_ws, size_t ws_size,
                              hipStream_t stream) {
    const float* preds   = (const float*)d_in[0];
    const float* targets = (const float*)d_in[1];
    float* out = (float*)d_out;
    float* partials = (float*)d_ws;
    const int B = in_sizes[0] / 384;   // 6 * 64 floats per batch

    const int total = B * 8;           // 8 lanes per batch
    const int grid  = (total + BLOCK - 1) / BLOCK;
    emd_kernel<<<grid, BLOCK, 0, stream>>>(preds, targets, partials);
    reduce_kernel<<<1, 256, 0, stream>>>(partials, out, grid);
}